// Round 1
// baseline (302.513 us; speedup 1.0000x reference)
//
#include <hip/hip_runtime.h>
#include <hip/hip_bf16.h>

#define N_NODES 20000
#define N_EDGES 40000
#define N_GRAPHS 500
#define D_IN 32
#define D_E 16
#define H1 100
#define H2 20
#define F1 50

#define ET1 16   // edges per block, layer-1 edge kernel
#define NT2 8    // nodes per block, Y2 GEMM
#define ET3 12   // edges per block, layer-2 edge kernel

// ---------------------------------------------------------------------------
// Layer 1 edge messages: msg[e,o] = sum_i x[src,i]*(b1[i*100+o] + sum_k ea[e,k]*W1[k,i*100+o])
// scatter-add into agg1[dst,o]
// ---------------------------------------------------------------------------
__global__ __launch_bounds__(128) void edge1_kernel(
    const float* __restrict__ x, const float* __restrict__ ea,
    const int* __restrict__ eidx, const float* __restrict__ nn1W,
    const float* __restrict__ nn1b, float* __restrict__ agg1)
{
  __shared__ float p[512][ET1];   // p[(i*16+k)][e] = x[src[e],i]*ea[e,k]
  __shared__ float sx[32][ET1];   // sx[i][e] = x[src[e],i]
  __shared__ float sea[16][ET1];  // sea[k][e]
  __shared__ int   sdst[ET1];

  const int tid = threadIdx.x;
  const int e0  = blockIdx.x * ET1;

  if (tid < ET1) sdst[tid] = eidx[N_EDGES + e0 + tid];
  for (int idx = tid; idx < ET1 * 16; idx += 128) {
    int e = idx >> 4, k = idx & 15;
    sea[k][e] = ea[(e0 + e) * D_E + k];
  }
  for (int idx = tid; idx < ET1 * 32; idx += 128) {
    int e = idx >> 5, i = idx & 31;
    int s = eidx[e0 + e];
    sx[i][e] = x[s * D_IN + i];
  }
  __syncthreads();
  for (int idx = tid; idx < 512 * ET1; idx += 128) {
    int j = idx >> 4, e = idx & 15;   // j = i*16 + k
    int i = j >> 4, k = j & 15;
    p[j][e] = sx[i][e] * sea[k][e];
  }
  __syncthreads();

  const int o = tid;
  if (o < H1) {
    float acc[ET1];
    #pragma unroll
    for (int e = 0; e < ET1; ++e) acc[e] = 0.f;

    // bias contribution: sum_i sx[i][e]*nn1b[i*100+o]
    for (int i = 0; i < D_IN; ++i) {
      float bv = nn1b[i * H1 + o];
      float pv[ET1];
      const float4* pr = (const float4*)&sx[i][0];
      *(float4*)&pv[0]  = pr[0];
      *(float4*)&pv[4]  = pr[1];
      *(float4*)&pv[8]  = pr[2];
      *(float4*)&pv[12] = pr[3];
      #pragma unroll
      for (int e = 0; e < ET1; ++e) acc[e] = fmaf(pv[e], bv, acc[e]);
    }

    // main contraction over j = (i,k)
    for (int i = 0; i < D_IN; ++i) {
      for (int k = 0; k < D_E; ++k) {
        float w = nn1W[k * (D_IN * H1) + i * H1 + o];
        float pv[ET1];
        const float4* pr = (const float4*)&p[i * 16 + k][0];
        *(float4*)&pv[0]  = pr[0];
        *(float4*)&pv[4]  = pr[1];
        *(float4*)&pv[8]  = pr[2];
        *(float4*)&pv[12] = pr[3];
        #pragma unroll
        for (int e = 0; e < ET1; ++e) acc[e] = fmaf(pv[e], w, acc[e]);
      }
    }

    #pragma unroll
    for (int e = 0; e < ET1; ++e)
      atomicAdd(&agg1[sdst[e] * H1 + o], acc[e]);
  }
}

// ---------------------------------------------------------------------------
// Node update 1: h1 = relu(agg1 + x @ root1 + bias1)
// ---------------------------------------------------------------------------
__global__ __launch_bounds__(128) void node1_kernel(
    const float* __restrict__ x, const float* __restrict__ agg1,
    const float* __restrict__ root1, const float* __restrict__ bias1,
    float* __restrict__ h1)
{
  __shared__ float sx[D_IN];
  const int n = blockIdx.x;
  const int o = threadIdx.x;
  if (o < D_IN) sx[o] = x[n * D_IN + o];
  __syncthreads();
  if (o < H1) {
    float v = agg1[n * H1 + o] + bias1[o];
    #pragma unroll
    for (int i = 0; i < D_IN; ++i) v = fmaf(sx[i], root1[i * H1 + o], v);
    h1[n * H1 + o] = fmaxf(v, 0.f);
  }
}

// ---------------------------------------------------------------------------
// Y2[n, k*20+o] = sum_i h1[n,i] * (k<16 ? W2[k, i*20+o] : b2[i*20+o])
// GEMM [20000,100] x [100,340]
// ---------------------------------------------------------------------------
__global__ __launch_bounds__(384) void y2_kernel(
    const float* __restrict__ h1, const float* __restrict__ nn2W,
    const float* __restrict__ nn2b, float* __restrict__ Y2)
{
  __shared__ float A[H1][NT2];  // A[i][nn] = h1[n0+nn, i]
  const int tid = threadIdx.x;
  const int n0 = blockIdx.x * NT2;
  for (int idx = tid; idx < NT2 * H1; idx += 384) {
    int nn = idx / H1, i = idx % H1;
    A[i][nn] = h1[(n0 + nn) * H1 + i];
  }
  __syncthreads();
  const int j = tid;
  if (j < 17 * H2) {
    const int k = j / H2, o = j % H2;
    const float* bp = (k < 16) ? (nn2W + k * (H1 * H2) + o) : (nn2b + o);
    float acc[NT2];
    #pragma unroll
    for (int nn = 0; nn < NT2; ++nn) acc[nn] = 0.f;
    for (int i = 0; i < H1; ++i) {
      float bv = bp[i * H2];
      float av[NT2];
      *(float4*)&av[0] = *(const float4*)&A[i][0];
      *(float4*)&av[4] = *(const float4*)&A[i][4];
      #pragma unroll
      for (int nn = 0; nn < NT2; ++nn) acc[nn] = fmaf(av[nn], bv, acc[nn]);
    }
    #pragma unroll
    for (int nn = 0; nn < NT2; ++nn) Y2[(n0 + nn) * 340 + j] = acc[nn];
  }
}

// ---------------------------------------------------------------------------
// Layer 2 edge pass: msg2[e,o] = Y2[src,320+o] + sum_k ea[e,k]*Y2[src,k*20+o]
// scatter-add into agg2[dst,o]
// ---------------------------------------------------------------------------
__global__ __launch_bounds__(256) void edge2_kernel(
    const float* __restrict__ ea, const int* __restrict__ eidx,
    const float* __restrict__ Y2, float* __restrict__ agg2)
{
  const int tid = threadIdx.x;
  const int el = tid / H2, o = tid % H2;
  const int e = blockIdx.x * ET3 + el;
  if (el < ET3 && e < N_EDGES) {
    const int s = eidx[e];
    const int d = eidx[N_EDGES + e];
    const float* yr = Y2 + s * 340;
    float m = yr[320 + o];
    #pragma unroll
    for (int k = 0; k < D_E; ++k)
      m = fmaf(ea[e * D_E + k], yr[k * H2 + o], m);
    atomicAdd(&agg2[d * H2 + o], m);
  }
}

// ---------------------------------------------------------------------------
// Node update 2: h2 = relu(agg2 + h1 @ root2 + bias2)
// ---------------------------------------------------------------------------
__global__ __launch_bounds__(256) void node2_kernel(
    const float* __restrict__ h1, const float* __restrict__ agg2,
    const float* __restrict__ root2, const float* __restrict__ bias2,
    float* __restrict__ h2)
{
  const int tid = threadIdx.x;
  const int nl = tid / H2, o = tid % H2;
  const int n = blockIdx.x * ET3 + nl;
  if (nl < ET3 && n < N_NODES) {
    float v = agg2[n * H2 + o] + bias2[o];
    #pragma unroll 4
    for (int i = 0; i < H1; ++i)
      v = fmaf(h1[n * H1 + i], root2[i * H2 + o], v);
    h2[n * H2 + o] = fmaxf(v, 0.f);
  }
}

// ---------------------------------------------------------------------------
// Sum-pool readout: g[batch[n], o] += h2[n, o]
// ---------------------------------------------------------------------------
__global__ __launch_bounds__(256) void pool_kernel(
    const float* __restrict__ h2, const int* __restrict__ batch,
    float* __restrict__ g)
{
  const int idx = blockIdx.x * 256 + threadIdx.x;
  if (idx < N_NODES * H2) {
    const int n = idx / H2, o = idx % H2;
    atomicAdd(&g[batch[n] * H2 + o], h2[idx]);
  }
}

// ---------------------------------------------------------------------------
// Final MLP: out[gr] = lin2_b + sum_f relu(lin1_b[f] + sum_o g[gr,o]*lin1_W[o,f]) * lin2_W[f]
// ---------------------------------------------------------------------------
__global__ __launch_bounds__(64) void final_kernel(
    const float* __restrict__ g, const float* __restrict__ lin1W,
    const float* __restrict__ lin1b, const float* __restrict__ lin2W,
    const float* __restrict__ lin2b, float* __restrict__ out)
{
  const int gr = blockIdx.x;
  const int t = threadIdx.x;
  float v = 0.f;
  if (t < F1) {
    float s = lin1b[t];
    #pragma unroll
    for (int o = 0; o < H2; ++o) s = fmaf(g[gr * H2 + o], lin1W[o * F1 + t], s);
    v = fmaxf(s, 0.f) * lin2W[t];
  }
  #pragma unroll
  for (int off = 32; off > 0; off >>= 1) v += __shfl_down(v, off, 64);
  if (t == 0) out[gr] = v + lin2b[0];
}

extern "C" void kernel_launch(void* const* d_in, const int* in_sizes, int n_in,
                              void* d_out, int out_size, void* d_ws, size_t ws_size,
                              hipStream_t stream) {
  const float* x     = (const float*)d_in[0];
  const float* ea    = (const float*)d_in[1];
  const int*   eidx  = (const int*)d_in[2];
  const int*   batch = (const int*)d_in[3];
  const float* nn1W  = (const float*)d_in[4];
  const float* nn1b  = (const float*)d_in[5];
  const float* root1 = (const float*)d_in[6];
  const float* bias1 = (const float*)d_in[7];
  const float* nn2W  = (const float*)d_in[8];
  const float* nn2b  = (const float*)d_in[9];
  const float* root2 = (const float*)d_in[10];
  const float* bias2 = (const float*)d_in[11];
  const float* lin1W = (const float*)d_in[12];
  const float* lin1b = (const float*)d_in[13];
  const float* lin2W = (const float*)d_in[14];
  const float* lin2b = (const float*)d_in[15];
  float* out = (float*)d_out;

  float* ws   = (float*)d_ws;
  float* agg1 = ws;                          // 2,000,000 floats
  float* agg2 = agg1 + N_NODES * H1;         //   400,000
  float* g    = agg2 + N_NODES * H2;         //    10,000
  float* h1   = g    + N_GRAPHS * H2;        // 2,000,000
  float* h2   = h1   + N_NODES * H1;         //   400,000
  float* Y2   = h2   + N_NODES * H2;         // 6,800,000

  // zero the atomic accumulators (agg1 | agg2 | g are contiguous)
  hipMemsetAsync(agg1, 0, (size_t)(N_NODES * H1 + N_NODES * H2 + N_GRAPHS * H2) * sizeof(float), stream);

  edge1_kernel<<<N_EDGES / ET1, 128, 0, stream>>>(x, ea, eidx, nn1W, nn1b, agg1);
  node1_kernel<<<N_NODES, 128, 0, stream>>>(x, agg1, root1, bias1, h1);
  y2_kernel<<<N_NODES / NT2, 384, 0, stream>>>(h1, nn2W, nn2b, Y2);
  edge2_kernel<<<(N_EDGES + ET3 - 1) / ET3, 256, 0, stream>>>(ea, eidx, Y2, agg2);
  node2_kernel<<<(N_NODES + ET3 - 1) / ET3, 256, 0, stream>>>(h1, agg2, root2, bias2, h2);
  pool_kernel<<<(N_NODES * H2 + 255) / 256, 256, 0, stream>>>(h2, batch, g);
  final_kernel<<<N_GRAPHS, 64, 0, stream>>>(g, lin1W, lin1b, lin2W, lin2b, out);
}